// Round 1
// baseline (801.856 us; speedup 1.0000x reference)
//
#include <hip/hip_runtime.h>
#include <math.h>

#define B_ 512
#define L_ 100
#define D_ 1024
#define POS_DIM_ 50
#define GM 51200
#define GN 1024
#define GK 1024
#define LDT 40   // padded LDS row stride (halfwords) for A tiles in gemm_hWn

typedef _Float16 half8 __attribute__((ext_vector_type(8)));
typedef _Float16 half4 __attribute__((ext_vector_type(4)));
typedef float floatx4 __attribute__((ext_vector_type(4)));

// ---------- fast device math ----------
__device__ __forceinline__ float fast_tanh(float x) {
    float e = __expf(2.0f * x);
    return 1.0f - 2.0f * __builtin_amdgcn_rcpf(e + 1.0f);
}
__device__ __forceinline__ float fast_sigmoid(float x) {
    return __builtin_amdgcn_rcpf(1.0f + __expf(-x));
}

// async global->LDS, 16B per lane; lds base must be wave-uniform
__device__ __forceinline__ void gll16(const void* g, void* l) {
    __builtin_amdgcn_global_load_lds(
        (const __attribute__((address_space(1))) void*)g,
        (__attribute__((address_space(3))) void*)l, 16, 0, 0);
}

// ---------- Kernel 1: docs (masked mean) + f16 hi/lo split of docs ----------
__global__ __launch_bounds__(256) void docs_kernel(
    const float* __restrict__ sent, const int* __restrict__ doc_lens,
    _Float16* __restrict__ docs_hi, _Float16* __restrict__ docs_lo)
{
    int b = blockIdx.x;
    int tid = threadIdx.x;
    int len = doc_lens[b];
    float inv = 1.0f / (float)len;
    const float* p = sent + (size_t)b * L_ * D_ + tid * 4;
    float4 acc = {0.f, 0.f, 0.f, 0.f};
    for (int l = 0; l < len; ++l) {
        float4 v = *(const float4*)(p + (size_t)l * D_);
        acc.x += v.x; acc.y += v.y; acc.z += v.z; acc.w += v.w;
    }
    float a[4] = {acc.x * inv, acc.y * inv, acc.z * inv, acc.w * inv};
    half4 h, lo;
    #pragma unroll
    for (int i = 0; i < 4; ++i) {
        _Float16 hi = (_Float16)a[i];
        h[i] = hi;
        lo[i] = (_Float16)(a[i] - (float)hi);
    }
    *(half4*)(docs_hi + (size_t)b * D_ + tid * 4) = h;
    *(half4*)(docs_lo + (size_t)b * D_ + tid * 4) = lo;
}

// ---------- Kernel 2: tiny embedding dots ----------
__global__ void emb_kernel(const float* __restrict__ abs_emb,
                           const float* __restrict__ rel_emb,
                           const float* __restrict__ abs_w,
                           const float* __restrict__ rel_w,
                           float* __restrict__ abs_p, float* __restrict__ rel_vals)
{
    int t = threadIdx.x;
    if (t < L_) {
        float a = 0.f;
        for (int j = 0; j < POS_DIM_; ++j) a += abs_emb[t * POS_DIM_ + j] * abs_w[j];
        abs_p[t] = a;
    }
    if (t < 10) {
        float r = 0.f;
        for (int j = 0; j < POS_DIM_; ++j) r += rel_emb[t * POS_DIM_ + j] * rel_w[j];
        rel_vals[t] = r;
    }
}

// ---------- Kernel 3: elementwise f16 hi/lo split of fc_w and sal_w ----------
__global__ __launch_bounds__(256) void wsplit_kernel(
    const float* __restrict__ fc_w, const float* __restrict__ sal_w,
    _Float16* __restrict__ fcw_hi, _Float16* __restrict__ fcw_lo,
    _Float16* __restrict__ salw_hi, _Float16* __restrict__ salw_lo)
{
    int id = blockIdx.x * 256 + threadIdx.x;
    int base = id * 4;
    const int NN = D_ * D_;
    const float* src; _Float16* dh; _Float16* dl; int off;
    if (base < NN) { src = fc_w; dh = fcw_hi; dl = fcw_lo; off = base; }
    else           { src = sal_w; dh = salw_hi; dl = salw_lo; off = base - NN; }
    float4 v = *(const float4*)(src + off);
    float a[4] = {v.x, v.y, v.z, v.w};
    half4 h, lo;
    #pragma unroll
    for (int i = 0; i < 4; ++i) {
        _Float16 hi = (_Float16)a[i];
        h[i] = hi;
        lo[i] = (_Float16)(a[i] - (float)hi);
    }
    *(half4*)(dh + off) = h;
    *(half4*)(dl + off) = lo;
}

// ---------- Kernel 4: transpose + f16 hi/lo split of nov_w ----------
__global__ __launch_bounds__(256) void convert_b(
    const float* __restrict__ B, _Float16* __restrict__ Bt_hi,
    _Float16* __restrict__ Bt_lo)
{
    __shared__ float ld[32][33];
    int k0 = blockIdx.x * 32, n0 = blockIdx.y * 32;
    int r  = threadIdx.x >> 3;
    int c4 = (threadIdx.x & 7) * 4;
    float4 v = *(const float4*)(B + (size_t)(k0 + r) * D_ + n0 + c4);
    ld[r][c4] = v.x; ld[r][c4 + 1] = v.y; ld[r][c4 + 2] = v.z; ld[r][c4 + 3] = v.w;
    __syncthreads();
    half4 h, l;
    #pragma unroll
    for (int i = 0; i < 4; ++i) {
        float x = ld[c4 + i][r];
        _Float16 hi = (_Float16)x;
        h[i] = hi;
        l[i] = (_Float16)(x - (float)hi);
    }
    *(half4*)(Bt_hi + (size_t)(n0 + r) * D_ + k0 + c4) = h;
    *(half4*)(Bt_lo + (size_t)(n0 + r) * D_ + k0 + c4) = l;
}

// ---------- Kernel 5: MFMA 3-pass f16-split GEMM for small GEMMs ----------
// A (hi/lo) [M,K] f16, B (hi/lo) [N,K] f16; all staging via global_load_lds.
// EPI 1: v = tanh(acc+X[n]) -> write f16 hi/lo pair (Oh, Ol)
// EPI 2: v = acc+X[n]       -> write fp32 O
template<int EPI>
__global__ __launch_bounds__(256, 2) void gemm_ms(
    const _Float16* __restrict__ Ah, const _Float16* __restrict__ Al,
    const _Float16* __restrict__ Bh, const _Float16* __restrict__ Bl,
    const float* __restrict__ X, float* __restrict__ O,
    _Float16* __restrict__ Oh, _Float16* __restrict__ Ol)
{
    __shared__ _Float16 sAh[128 * 32];
    __shared__ _Float16 sAl[128 * 32];
    __shared__ _Float16 sBh[128 * 32];
    __shared__ _Float16 sBl[128 * 32];

    int tid = threadIdx.x;
    int wave = tid >> 6, lane = tid & 63;
    int n0 = blockIdx.x * 128, m0 = blockIdx.y * 128;
    int wm = (wave >> 1) * 64, wn = (wave & 1) * 64;
    int tm = lane & 15, quad = lane >> 4;

    floatx4 acc[4][4];
    #pragma unroll
    for (int i = 0; i < 4; ++i)
        #pragma unroll
        for (int j = 0; j < 4; ++j)
            acc[i][j] = (floatx4){0.f, 0.f, 0.f, 0.f};

    int grow = lane >> 2;          // 0..15
    int gcol = (lane & 3) * 8;     // halfword offset
    const _Float16* pAh = Ah + (size_t)(m0 + wave * 32 + grow) * GK + gcol;
    const _Float16* pAl = Al + (size_t)(m0 + wave * 32 + grow) * GK + gcol;
    const _Float16* pBh = Bh + (size_t)(n0 + wave * 32 + grow) * GK + gcol;
    const _Float16* pBl = Bl + (size_t)(n0 + wave * 32 + grow) * GK + gcol;
    _Float16* lAh = sAh + wave * 32 * 32;
    _Float16* lAl = sAl + wave * 32 * 32;
    _Float16* lBh = sBh + wave * 32 * 32;
    _Float16* lBl = sBl + wave * 32 * 32;

    #pragma unroll 1
    for (int k0 = 0; k0 < GK; k0 += 32) {
        __syncthreads();   // previous iteration's fragment reads complete
        gll16(pAh + k0, lAh);
        gll16(pAh + 16 * GK + k0, lAh + 16 * 32);
        gll16(pAl + k0, lAl);
        gll16(pAl + 16 * GK + k0, lAl + 16 * 32);
        gll16(pBh + k0, lBh);
        gll16(pBh + 16 * GK + k0, lBh + 16 * 32);
        gll16(pBl + k0, lBl);
        gll16(pBl + 16 * GK + k0, lBl + 16 * 32);
        __syncthreads();   // drains vmcnt(0): LDS tile ready

        half8 fah[4], fal[4], fbh[4], fbl[4];
        #pragma unroll
        for (int mt = 0; mt < 4; ++mt) {
            int base = (wm + mt * 16 + tm) * 32 + quad * 8;
            fah[mt] = *(const half8*)(sAh + base);
            fal[mt] = *(const half8*)(sAl + base);
        }
        #pragma unroll
        for (int nt = 0; nt < 4; ++nt) {
            int base = (wn + nt * 16 + tm) * 32 + quad * 8;
            fbh[nt] = *(const half8*)(sBh + base);
            fbl[nt] = *(const half8*)(sBl + base);
        }
        #pragma unroll
        for (int mt = 0; mt < 4; ++mt)
            #pragma unroll
            for (int nt = 0; nt < 4; ++nt) {
                acc[mt][nt] = __builtin_amdgcn_mfma_f32_16x16x32_f16(
                    fah[mt], fbh[nt], acc[mt][nt], 0, 0, 0);
                acc[mt][nt] = __builtin_amdgcn_mfma_f32_16x16x32_f16(
                    fah[mt], fbl[nt], acc[mt][nt], 0, 0, 0);
                acc[mt][nt] = __builtin_amdgcn_mfma_f32_16x16x32_f16(
                    fal[mt], fbh[nt], acc[mt][nt], 0, 0, 0);
            }
    }

    #pragma unroll
    for (int mt = 0; mt < 4; ++mt) {
        #pragma unroll
        for (int nt = 0; nt < 4; ++nt) {
            int col = n0 + wn + nt * 16 + tm;
            int rowb = m0 + wm + mt * 16 + quad * 4;
            float xv = X[col];
            #pragma unroll
            for (int r = 0; r < 4; ++r) {
                float v = acc[mt][nt][r];
                if (EPI == 1) {
                    v = tanhf(v + xv);
                    _Float16 hi = (_Float16)v;
                    Oh[(size_t)(rowb + r) * GN + col] = hi;
                    Ol[(size_t)(rowb + r) * GN + col] = (_Float16)(v - (float)hi);
                } else {
                    O[(size_t)(rowb + r) * GN + col] = v + xv;
                }
            }
        }
    }
}

// ---------- Kernel 6: MFMA f16-split GEMM: hWn = sent @ nov_w ----------
// A fp32 split on the fly (VALU); B (pre-split) staged via global_load_lds.
// XCD swizzle: d = g*64 + n*8 + i, m = g*8 + i  (8 n-blocks of a slab share d%8)
__global__ __launch_bounds__(256, 2) void gemm_hWn(
    const float* __restrict__ A, const _Float16* __restrict__ Bt_hi,
    const _Float16* __restrict__ Bt_lo, float* __restrict__ C)
{
    __shared__ _Float16 As_hi[128 * LDT];
    __shared__ _Float16 As_lo[128 * LDT];
    __shared__ _Float16 Bs_hi[128 * 32];
    __shared__ _Float16 Bs_lo[128 * 32];

    int tid  = threadIdx.x;
    int wave = tid >> 6, lane = tid & 63;
    int d = blockIdx.x;
    int islab = d & 7, nblk = (d >> 3) & 7, g = d >> 6;
    int m0 = (g * 8 + islab) * 128;
    int n0 = nblk * 128;
    int wm = (wave >> 1) * 64, wn = (wave & 1) * 64;
    int tm   = lane & 15;
    int quad = lane >> 4;

    floatx4 acc[4][4];
    #pragma unroll
    for (int i = 0; i < 4; ++i)
        #pragma unroll
        for (int j = 0; j < 4; ++j)
            acc[i][j] = (floatx4){0.f, 0.f, 0.f, 0.f};

    // A staging: thread covers (row, 16-elem k-half)
    int sr = tid >> 1;
    int sh = tid & 1;
    const float* Ap = A + (size_t)(m0 + sr) * GK + sh * 16;
    int sbase = sr * LDT + sh * 16;

    // B staging via gll: wave covers rows [wave*32, wave*32+32)
    int grow = lane >> 2;
    int gcol = (lane & 3) * 8;
    const _Float16* pBh = Bt_hi + (size_t)(n0 + wave * 32 + grow) * GK + gcol;
    const _Float16* pBl = Bt_lo + (size_t)(n0 + wave * 32 + grow) * GK + gcol;
    _Float16* lBh = Bs_hi + wave * 32 * 32;
    _Float16* lBl = Bs_lo + wave * 32 * 32;

    #pragma unroll 1
    for (int k0 = 0; k0 < GK; k0 += 32) {
        float4 a0 = *(const float4*)(Ap + k0);
        float4 a1 = *(const float4*)(Ap + k0 + 4);
        float4 a2 = *(const float4*)(Ap + k0 + 8);
        float4 a3 = *(const float4*)(Ap + k0 + 12);

        half8 ah0, ah1, al0, al1;
        float af[16] = {a0.x, a0.y, a0.z, a0.w, a1.x, a1.y, a1.z, a1.w,
                        a2.x, a2.y, a2.z, a2.w, a3.x, a3.y, a3.z, a3.w};
        #pragma unroll
        for (int i = 0; i < 8; ++i) {
            _Float16 h = (_Float16)af[i];
            ah0[i] = h;
            al0[i] = (_Float16)(af[i] - (float)h);
        }
        #pragma unroll
        for (int i = 0; i < 8; ++i) {
            _Float16 h = (_Float16)af[8 + i];
            ah1[i] = h;
            al1[i] = (_Float16)(af[8 + i] - (float)h);
        }

        __syncthreads();   // previous iteration's fragment reads complete
        // B DMA into LDS
        gll16(pBh + k0, lBh);
        gll16(pBh + 16 * GK + k0, lBh + 16 * 32);
        gll16(pBl + k0, lBl);
        gll16(pBl + 16 * GK + k0, lBl + 16 * 32);
        // A stores
        *(half8*)(As_hi + sbase)     = ah0;
        *(half8*)(As_hi + sbase + 8) = ah1;
        *(half8*)(As_lo + sbase)     = al0;
        *(half8*)(As_lo + sbase + 8) = al1;
        __syncthreads();   // drains vmcnt (gll) + lgkm (stores)

        half8 fa_hi[4], fa_lo[4], fb_hi[4], fb_lo[4];
        #pragma unroll
        for (int mt = 0; mt < 4; ++mt) {
            int row = (wm + mt * 16 + tm) * LDT + quad * 8;
            fa_hi[mt] = *(const half8*)(As_hi + row);
            fa_lo[mt] = *(const half8*)(As_lo + row);
        }
        #pragma unroll
        for (int nt = 0; nt < 4; ++nt) {
            int row = (wn + nt * 16 + tm) * 32 + quad * 8;
            fb_hi[nt] = *(const half8*)(Bs_hi + row);
            fb_lo[nt] = *(const half8*)(Bs_lo + row);
        }
        #pragma unroll
        for (int mt = 0; mt < 4; ++mt)
            #pragma unroll
            for (int nt = 0; nt < 4; ++nt) {
                acc[mt][nt] = __builtin_amdgcn_mfma_f32_16x16x32_f16(
                    fa_hi[mt], fb_hi[nt], acc[mt][nt], 0, 0, 0);
                acc[mt][nt] = __builtin_amdgcn_mfma_f32_16x16x32_f16(
                    fa_hi[mt], fb_lo[nt], acc[mt][nt], 0, 0, 0);
                acc[mt][nt] = __builtin_amdgcn_mfma_f32_16x16x32_f16(
                    fa_lo[mt], fb_hi[nt], acc[mt][nt], 0, 0, 0);
            }
    }

    #pragma unroll
    for (int mt = 0; mt < 4; ++mt) {
        #pragma unroll
        for (int nt = 0; nt < 4; ++nt) {
            int col = n0 + wn + nt * 16 + tm;
            int rowb = m0 + wm + mt * 16 + quad * 4;
            #pragma unroll
            for (int r = 0; r < 4; ++r)
                C[(size_t)(rowb + r) * GN + col] = acc[mt][nt][r];
        }
    }
}

// ---------- Kernel 7: scan — one wave per batch, all-register ----------
__global__ __launch_bounds__(64) void scan_kernel(
    const float* __restrict__ sent, const float* __restrict__ hWn,
    const float* __restrict__ u, const float* __restrict__ abs_p,
    const float* __restrict__ rel_vals, const float* __restrict__ bias,
    const int* __restrict__ doc_lens, float* __restrict__ out)
{
    int b = blockIdx.x;
    int lane = threadIdx.x;
    int len = doc_lens[b];
    float lenf = (float)len;

    for (int l = len + lane; l < L_; l += 64) out[b * L_ + l] = 0.f;

    // lane owns cols {lane*4 + j*256 : j=0..3, +0..3}
    const float* ub = u + (size_t)b * D_ + lane * 4;
    float ur[16], s[16];
    #pragma unroll
    for (int j = 0; j < 4; ++j) {
        *(float4*)(ur + 4 * j) = *(const float4*)(ub + 256 * j);
    }
    #pragma unroll
    for (int i = 0; i < 16; ++i) s[i] = 0.f;

    const float* sb = sent + (size_t)b * L_ * D_ + lane * 4;
    const float* wb = hWn  + (size_t)b * L_ * D_ + lane * 4;
    float biasv = bias[0];

    float hA[16], wA[16], hB[16], wB[16];

    auto loadrow = [&](int row, float* hh, float* ww) {
        const float* ph = sb + (size_t)row * D_;
        const float* pw = wb + (size_t)row * D_;
        #pragma unroll
        for (int j = 0; j < 4; ++j) {
            *(float4*)(hh + 4 * j) = *(const float4*)(ph + 256 * j);
            *(float4*)(ww + 4 * j) = *(const float4*)(pw + 256 * j);
        }
    };

    auto step = [&](int t, const float* hh, const float* ww) {
        float r1 = 0.f, r2 = 0.f;
        #pragma unroll
        for (int i = 0; i < 16; ++i) {
            r1 = fmaf(ww[i], fast_tanh(s[i]), r1);
            r2 = fmaf(hh[i], ur[i], r2);
        }
        #pragma unroll
        for (int off = 32; off; off >>= 1) {
            r1 += __shfl_xor(r1, off);
            r2 += __shfl_xor(r2, off);
        }
        int ridx = (int)rintf((float)(t + 1) * 9.0f / lenf);
        ridx = min(max(ridx, 0), 9);
        float pre = r2 + abs_p[t] + rel_vals[ridx] + biasv - r1;
        float prob = fast_sigmoid(pre);
        if (lane == 0) out[b * L_ + t] = prob;
        #pragma unroll
        for (int i = 0; i < 16; ++i) s[i] = fmaf(prob, hh[i], s[i]);
    };

    loadrow(0, hA, wA);
    int t = 0;
    while (true) {
        int tn = min(t + 1, len - 1);
        loadrow(tn, hB, wB);
        step(t, hA, wA);
        ++t; if (t >= len) break;
        tn = min(t + 1, len - 1);
        loadrow(tn, hA, wA);
        step(t, hB, wB);
        ++t; if (t >= len) break;
    }
}

// ---------- launch ----------
extern "C" void kernel_launch(void* const* d_in, const int* in_sizes, int n_in,
                              void* d_out, int out_size, void* d_ws, size_t ws_size,
                              hipStream_t stream)
{
    const float* sent      = (const float*)d_in[0];
    const float* fc_w      = (const float*)d_in[1];
    const float* fc_b      = (const float*)d_in[2];
    const float* content_w = (const float*)d_in[3];
    const float* sal_w     = (const float*)d_in[4];
    const float* nov_w     = (const float*)d_in[5];
    const float* abs_emb   = (const float*)d_in[6];
    const float* rel_emb   = (const float*)d_in[7];
    const float* abs_w     = (const float*)d_in[8];
    const float* rel_w     = (const float*)d_in[9];
    const float* bias      = (const float*)d_in[10];
    const int*   doc_lens  = (const int*)d_in[11];
    float* out = (float*)d_out;

    char* ws = (char*)d_ws;
    const size_t MB = 1024 * 1024;
    _Float16* docs_hi = (_Float16*)(ws);             // 1 MiB
    _Float16* docs_lo = (_Float16*)(ws + 1 * MB);    // 1 MiB
    _Float16* dv_hi   = (_Float16*)(ws + 2 * MB);    // 1 MiB
    _Float16* dv_lo   = (_Float16*)(ws + 3 * MB);    // 1 MiB
    float*    u       = (float*)(ws + 4 * MB);       // 2 MiB
    float*    abs_p   = (float*)(ws + 6 * MB);
    float*    rel_vals= (float*)(ws + 6 * MB + 512);
    _Float16* fcw_hi  = (_Float16*)(ws + 7 * MB);    // 2 MiB
    _Float16* fcw_lo  = (_Float16*)(ws + 9 * MB);    // 2 MiB
    _Float16* salw_hi = (_Float16*)(ws + 11 * MB);   // 2 MiB
    _Float16* salw_lo = (_Float16*)(ws + 13 * MB);   // 2 MiB
    _Float16* Bt_hi   = (_Float16*)(ws + 15 * MB);   // 2 MiB
    _Float16* Bt_lo   = (_Float16*)(ws + 17 * MB);   // 2 MiB
    float*    hWn     = (float*)(ws + 20 * MB);      // 200 MiB

    // 1) docs masked mean + split
    docs_kernel<<<dim3(B_), 256, 0, stream>>>(sent, doc_lens, docs_hi, docs_lo);

    // 2) embedding dots
    emb_kernel<<<dim3(1), 128, 0, stream>>>(abs_emb, rel_emb, abs_w, rel_w, abs_p, rel_vals);

    // 3) split fc_w / sal_w (already [N,K] layout)
    wsplit_kernel<<<dim3(2 * D_ * D_ / (256 * 4)), 256, 0, stream>>>(
        fc_w, sal_w, fcw_hi, fcw_lo, salw_hi, salw_lo);

    // 4) transpose + split nov_w
    convert_b<<<dim3(32, 32), 256, 0, stream>>>(nov_w, Bt_hi, Bt_lo);

    // 5) hWn = sent @ nov_w  (XCD-swizzled 1D grid: 50 groups * 64 blocks)
    gemm_hWn<<<dim3(3200), 256, 0, stream>>>(sent, Bt_hi, Bt_lo, hWn);

    // 6) doc_vec = tanh(docs @ fc_w^T + fc_b) -> f16 pair
    gemm_ms<1><<<dim3(D_ / 128, B_ / 128), 256, 0, stream>>>(
        docs_hi, docs_lo, fcw_hi, fcw_lo, fc_b, nullptr, dv_hi, dv_lo);

    // 7) u = doc_vec @ sal_w^T + content_w -> fp32
    gemm_ms<2><<<dim3(D_ / 128, B_ / 128), 256, 0, stream>>>(
        dv_hi, dv_lo, salw_hi, salw_lo, content_w, u, nullptr, nullptr);

    // 8) scan: one wave per batch
    scan_kernel<<<dim3(B_), 64, 0, stream>>>(
        sent, hWn, u, abs_p, rel_vals, bias, doc_lens, out);
}

// Round 2
// 776.067 us; speedup vs baseline: 1.0332x; 1.0332x over previous
//
#include <hip/hip_runtime.h>
#include <math.h>

#define B_ 512
#define L_ 100
#define D_ 1024
#define POS_DIM_ 50
#define GM 51200
#define GN 1024
#define GK 1024
#define LDT 40   // padded LDS row stride (halfwords) for A tiles in gemm_hWn

typedef _Float16 half8 __attribute__((ext_vector_type(8)));
typedef _Float16 half4 __attribute__((ext_vector_type(4)));
typedef float floatx4 __attribute__((ext_vector_type(4)));

// ---------- fast device math ----------
__device__ __forceinline__ float fast_tanh(float x) {
    float e = __expf(2.0f * x);
    return 1.0f - 2.0f * __builtin_amdgcn_rcpf(e + 1.0f);
}
__device__ __forceinline__ float fast_sigmoid(float x) {
    return __builtin_amdgcn_rcpf(1.0f + __expf(-x));
}

// async global->LDS, 16B per lane; lds base must be wave-uniform
__device__ __forceinline__ void gll16(const void* g, void* l) {
    __builtin_amdgcn_global_load_lds(
        (const __attribute__((address_space(1))) void*)g,
        (__attribute__((address_space(3))) void*)l, 16, 0, 0);
}

// ---------- Kernel 1: docs (masked mean) + f16 hi/lo split of docs ----------
__global__ __launch_bounds__(256) void docs_kernel(
    const float* __restrict__ sent, const int* __restrict__ doc_lens,
    _Float16* __restrict__ docs_hi, _Float16* __restrict__ docs_lo)
{
    int b = blockIdx.x;
    int tid = threadIdx.x;
    int len = doc_lens[b];
    float inv = 1.0f / (float)len;
    const float* p = sent + (size_t)b * L_ * D_ + tid * 4;
    float4 acc = {0.f, 0.f, 0.f, 0.f};
    float4 acc2 = {0.f, 0.f, 0.f, 0.f};
    int l = 0;
    for (; l + 1 < len; l += 2) {
        float4 v0 = *(const float4*)(p + (size_t)l * D_);
        float4 v1 = *(const float4*)(p + (size_t)(l + 1) * D_);
        acc.x += v0.x; acc.y += v0.y; acc.z += v0.z; acc.w += v0.w;
        acc2.x += v1.x; acc2.y += v1.y; acc2.z += v1.z; acc2.w += v1.w;
    }
    if (l < len) {
        float4 v0 = *(const float4*)(p + (size_t)l * D_);
        acc.x += v0.x; acc.y += v0.y; acc.z += v0.z; acc.w += v0.w;
    }
    acc.x += acc2.x; acc.y += acc2.y; acc.z += acc2.z; acc.w += acc2.w;
    float a[4] = {acc.x * inv, acc.y * inv, acc.z * inv, acc.w * inv};
    half4 h, lo;
    #pragma unroll
    for (int i = 0; i < 4; ++i) {
        _Float16 hi = (_Float16)a[i];
        h[i] = hi;
        lo[i] = (_Float16)(a[i] - (float)hi);
    }
    *(half4*)(docs_hi + (size_t)b * D_ + tid * 4) = h;
    *(half4*)(docs_lo + (size_t)b * D_ + tid * 4) = lo;
}

// ---------- Kernel 2: tiny embedding dots ----------
__global__ void emb_kernel(const float* __restrict__ abs_emb,
                           const float* __restrict__ rel_emb,
                           const float* __restrict__ abs_w,
                           const float* __restrict__ rel_w,
                           float* __restrict__ abs_p, float* __restrict__ rel_vals)
{
    int t = threadIdx.x;
    if (t < L_) {
        float a = 0.f;
        for (int j = 0; j < POS_DIM_; ++j) a += abs_emb[t * POS_DIM_ + j] * abs_w[j];
        abs_p[t] = a;
    }
    if (t < 10) {
        float r = 0.f;
        for (int j = 0; j < POS_DIM_; ++j) r += rel_emb[t * POS_DIM_ + j] * rel_w[j];
        rel_vals[t] = r;
    }
}

// ---------- Kernel 3: elementwise f16 hi/lo split of fc_w and sal_w ----------
__global__ __launch_bounds__(256) void wsplit_kernel(
    const float* __restrict__ fc_w, const float* __restrict__ sal_w,
    _Float16* __restrict__ fcw_hi, _Float16* __restrict__ fcw_lo,
    _Float16* __restrict__ salw_hi, _Float16* __restrict__ salw_lo)
{
    int id = blockIdx.x * 256 + threadIdx.x;
    int base = id * 4;
    const int NN = D_ * D_;
    const float* src; _Float16* dh; _Float16* dl; int off;
    if (base < NN) { src = fc_w; dh = fcw_hi; dl = fcw_lo; off = base; }
    else           { src = sal_w; dh = salw_hi; dl = salw_lo; off = base - NN; }
    float4 v = *(const float4*)(src + off);
    float a[4] = {v.x, v.y, v.z, v.w};
    half4 h, lo;
    #pragma unroll
    for (int i = 0; i < 4; ++i) {
        _Float16 hi = (_Float16)a[i];
        h[i] = hi;
        lo[i] = (_Float16)(a[i] - (float)hi);
    }
    *(half4*)(dh + off) = h;
    *(half4*)(dl + off) = lo;
}

// ---------- Kernel 4: transpose + f16 hi/lo split of nov_w ----------
__global__ __launch_bounds__(256) void convert_b(
    const float* __restrict__ B, _Float16* __restrict__ Bt_hi,
    _Float16* __restrict__ Bt_lo)
{
    __shared__ float ld[32][33];
    int k0 = blockIdx.x * 32, n0 = blockIdx.y * 32;
    int r  = threadIdx.x >> 3;
    int c4 = (threadIdx.x & 7) * 4;
    float4 v = *(const float4*)(B + (size_t)(k0 + r) * D_ + n0 + c4);
    ld[r][c4] = v.x; ld[r][c4 + 1] = v.y; ld[r][c4 + 2] = v.z; ld[r][c4 + 3] = v.w;
    __syncthreads();
    half4 h, l;
    #pragma unroll
    for (int i = 0; i < 4; ++i) {
        float x = ld[c4 + i][r];
        _Float16 hi = (_Float16)x;
        h[i] = hi;
        l[i] = (_Float16)(x - (float)hi);
    }
    *(half4*)(Bt_hi + (size_t)(n0 + r) * D_ + k0 + c4) = h;
    *(half4*)(Bt_lo + (size_t)(n0 + r) * D_ + k0 + c4) = l;
}

// ---------- Kernel 5: MFMA 3-pass f16-split GEMM for small GEMMs ----------
// A (hi/lo) [M,K] f16, B (hi/lo) [N,K] f16; all staging via global_load_lds.
// EPI 1: v = tanh(acc+X[n]) -> write f16 hi/lo pair (Oh, Ol)
// EPI 2: v = acc+X[n]       -> write fp32 O
template<int EPI>
__global__ __launch_bounds__(256, 2) void gemm_ms(
    const _Float16* __restrict__ Ah, const _Float16* __restrict__ Al,
    const _Float16* __restrict__ Bh, const _Float16* __restrict__ Bl,
    const float* __restrict__ X, float* __restrict__ O,
    _Float16* __restrict__ Oh, _Float16* __restrict__ Ol)
{
    __shared__ _Float16 sAh[128 * 32];
    __shared__ _Float16 sAl[128 * 32];
    __shared__ _Float16 sBh[128 * 32];
    __shared__ _Float16 sBl[128 * 32];

    int tid = threadIdx.x;
    int wave = tid >> 6, lane = tid & 63;
    int n0 = blockIdx.x * 128, m0 = blockIdx.y * 128;
    int wm = (wave >> 1) * 64, wn = (wave & 1) * 64;
    int tm = lane & 15, quad = lane >> 4;

    floatx4 acc[4][4];
    #pragma unroll
    for (int i = 0; i < 4; ++i)
        #pragma unroll
        for (int j = 0; j < 4; ++j)
            acc[i][j] = (floatx4){0.f, 0.f, 0.f, 0.f};

    int grow = lane >> 2;          // 0..15
    int gcol = (lane & 3) * 8;     // halfword offset
    const _Float16* pAh = Ah + (size_t)(m0 + wave * 32 + grow) * GK + gcol;
    const _Float16* pAl = Al + (size_t)(m0 + wave * 32 + grow) * GK + gcol;
    const _Float16* pBh = Bh + (size_t)(n0 + wave * 32 + grow) * GK + gcol;
    const _Float16* pBl = Bl + (size_t)(n0 + wave * 32 + grow) * GK + gcol;
    _Float16* lAh = sAh + wave * 32 * 32;
    _Float16* lAl = sAl + wave * 32 * 32;
    _Float16* lBh = sBh + wave * 32 * 32;
    _Float16* lBl = sBl + wave * 32 * 32;

    #pragma unroll 1
    for (int k0 = 0; k0 < GK; k0 += 32) {
        __syncthreads();   // previous iteration's fragment reads complete
        gll16(pAh + k0, lAh);
        gll16(pAh + 16 * GK + k0, lAh + 16 * 32);
        gll16(pAl + k0, lAl);
        gll16(pAl + 16 * GK + k0, lAl + 16 * 32);
        gll16(pBh + k0, lBh);
        gll16(pBh + 16 * GK + k0, lBh + 16 * 32);
        gll16(pBl + k0, lBl);
        gll16(pBl + 16 * GK + k0, lBl + 16 * 32);
        __syncthreads();   // drains vmcnt(0): LDS tile ready

        half8 fah[4], fal[4], fbh[4], fbl[4];
        #pragma unroll
        for (int mt = 0; mt < 4; ++mt) {
            int base = (wm + mt * 16 + tm) * 32 + quad * 8;
            fah[mt] = *(const half8*)(sAh + base);
            fal[mt] = *(const half8*)(sAl + base);
        }
        #pragma unroll
        for (int nt = 0; nt < 4; ++nt) {
            int base = (wn + nt * 16 + tm) * 32 + quad * 8;
            fbh[nt] = *(const half8*)(sBh + base);
            fbl[nt] = *(const half8*)(sBl + base);
        }
        #pragma unroll
        for (int mt = 0; mt < 4; ++mt)
            #pragma unroll
            for (int nt = 0; nt < 4; ++nt) {
                acc[mt][nt] = __builtin_amdgcn_mfma_f32_16x16x32_f16(
                    fah[mt], fbh[nt], acc[mt][nt], 0, 0, 0);
                acc[mt][nt] = __builtin_amdgcn_mfma_f32_16x16x32_f16(
                    fah[mt], fbl[nt], acc[mt][nt], 0, 0, 0);
                acc[mt][nt] = __builtin_amdgcn_mfma_f32_16x16x32_f16(
                    fal[mt], fbh[nt], acc[mt][nt], 0, 0, 0);
            }
    }

    #pragma unroll
    for (int mt = 0; mt < 4; ++mt) {
        #pragma unroll
        for (int nt = 0; nt < 4; ++nt) {
            int col = n0 + wn + nt * 16 + tm;
            int rowb = m0 + wm + mt * 16 + quad * 4;
            float xv = X[col];
            #pragma unroll
            for (int r = 0; r < 4; ++r) {
                float v = acc[mt][nt][r];
                if (EPI == 1) {
                    v = tanhf(v + xv);
                    _Float16 hi = (_Float16)v;
                    Oh[(size_t)(rowb + r) * GN + col] = hi;
                    Ol[(size_t)(rowb + r) * GN + col] = (_Float16)(v - (float)hi);
                } else {
                    O[(size_t)(rowb + r) * GN + col] = v + xv;
                }
            }
        }
    }
}

// ---------- Kernel 6: MFMA f16-split GEMM: hWn = sent @ nov_w ----------
// A fp32 split on the fly (VALU); B (pre-split) staged via global_load_lds.
// B-tile LDS XOR-swizzle (T2): chunk' = chunk ^ ((row>>1)&3).
// gll dest is linear (rule #21), so the swizzle is applied by permuting the
// per-lane GLOBAL source chunk; ds_read applies the same XOR. Bank-slot of
// (row,chunk') = (4*row + chunk') mod 8 -> all 8 slots covered per 8 rows.
__global__ __launch_bounds__(256, 2) void gemm_hWn(
    const float* __restrict__ A, const _Float16* __restrict__ Bt_hi,
    const _Float16* __restrict__ Bt_lo, float* __restrict__ C)
{
    __shared__ _Float16 As_hi[128 * LDT];
    __shared__ _Float16 As_lo[128 * LDT];
    __shared__ _Float16 Bs_hi[128 * 32];
    __shared__ _Float16 Bs_lo[128 * 32];

    int tid  = threadIdx.x;
    int wave = tid >> 6, lane = tid & 63;
    int d = blockIdx.x;
    int islab = d & 7, nblk = (d >> 3) & 7, g = d >> 6;
    int m0 = (g * 8 + islab) * 128;
    int n0 = nblk * 128;
    int wm = (wave >> 1) * 64, wn = (wave & 1) * 64;
    int tm   = lane & 15;
    int quad = lane >> 4;

    floatx4 acc[4][4];
    #pragma unroll
    for (int i = 0; i < 4; ++i)
        #pragma unroll
        for (int j = 0; j < 4; ++j)
            acc[i][j] = (floatx4){0.f, 0.f, 0.f, 0.f};

    // A staging: thread covers (row, 16-elem k-half)
    int sr = tid >> 1;
    int sh = tid & 1;
    const float* Ap = A + (size_t)(m0 + sr) * GK + sh * 16;
    int sbase = sr * LDT + sh * 16;

    // B staging via gll: wave covers rows [wave*32, wave*32+32)
    // source chunk pre-swizzled: lane (r=lane>>2, c=lane&3) fetches global
    // chunk c ^ ((r>>1)&3) so LDS slot c holds that chunk.
    int grow = lane >> 2;
    int gswz = ((lane & 3) ^ ((lane >> 3) & 3)) * 8;   // halfword offset
    const _Float16* pBh = Bt_hi + (size_t)(n0 + wave * 32 + grow) * GK + gswz;
    const _Float16* pBl = Bt_lo + (size_t)(n0 + wave * 32 + grow) * GK + gswz;
    _Float16* lBh = Bs_hi + wave * 32 * 32;
    _Float16* lBl = Bs_lo + wave * 32 * 32;

    #pragma unroll 1
    for (int k0 = 0; k0 < GK; k0 += 32) {
        float4 a0 = *(const float4*)(Ap + k0);
        float4 a1 = *(const float4*)(Ap + k0 + 4);
        float4 a2 = *(const float4*)(Ap + k0 + 8);
        float4 a3 = *(const float4*)(Ap + k0 + 12);

        half8 ah0, ah1, al0, al1;
        float af[16] = {a0.x, a0.y, a0.z, a0.w, a1.x, a1.y, a1.z, a1.w,
                        a2.x, a2.y, a2.z, a2.w, a3.x, a3.y, a3.z, a3.w};
        #pragma unroll
        for (int i = 0; i < 8; ++i) {
            _Float16 h = (_Float16)af[i];
            ah0[i] = h;
            al0[i] = (_Float16)(af[i] - (float)h);
        }
        #pragma unroll
        for (int i = 0; i < 8; ++i) {
            _Float16 h = (_Float16)af[8 + i];
            ah1[i] = h;
            al1[i] = (_Float16)(af[8 + i] - (float)h);
        }

        __syncthreads();   // previous iteration's fragment reads complete
        // B DMA into LDS (linear dest; source chunk pre-swizzled)
        gll16(pBh + k0, lBh);
        gll16(pBh + 16 * GK + k0, lBh + 16 * 32);
        gll16(pBl + k0, lBl);
        gll16(pBl + 16 * GK + k0, lBl + 16 * 32);
        // A stores
        *(half8*)(As_hi + sbase)     = ah0;
        *(half8*)(As_hi + sbase + 8) = ah1;
        *(half8*)(As_lo + sbase)     = al0;
        *(half8*)(As_lo + sbase + 8) = al1;
        __syncthreads();   // drains vmcnt (gll) + lgkm (stores)

        half8 fa_hi[4], fa_lo[4], fb_hi[4], fb_lo[4];
        #pragma unroll
        for (int mt = 0; mt < 4; ++mt) {
            int row = (wm + mt * 16 + tm) * LDT + quad * 8;
            fa_hi[mt] = *(const half8*)(As_hi + row);
            fa_lo[mt] = *(const half8*)(As_lo + row);
        }
        #pragma unroll
        for (int nt = 0; nt < 4; ++nt) {
            int row = wn + nt * 16 + tm;
            int rbase = row * 32 + ((quad ^ ((row >> 1) & 3)) << 3);
            fb_hi[nt] = *(const half8*)(Bs_hi + rbase);
            fb_lo[nt] = *(const half8*)(Bs_lo + rbase);
        }
        #pragma unroll
        for (int mt = 0; mt < 4; ++mt)
            #pragma unroll
            for (int nt = 0; nt < 4; ++nt) {
                acc[mt][nt] = __builtin_amdgcn_mfma_f32_16x16x32_f16(
                    fa_hi[mt], fb_hi[nt], acc[mt][nt], 0, 0, 0);
                acc[mt][nt] = __builtin_amdgcn_mfma_f32_16x16x32_f16(
                    fa_hi[mt], fb_lo[nt], acc[mt][nt], 0, 0, 0);
                acc[mt][nt] = __builtin_amdgcn_mfma_f32_16x16x32_f16(
                    fa_lo[mt], fb_hi[nt], acc[mt][nt], 0, 0, 0);
            }
    }

    #pragma unroll
    for (int mt = 0; mt < 4; ++mt) {
        #pragma unroll
        for (int nt = 0; nt < 4; ++nt) {
            int col = n0 + wn + nt * 16 + tm;
            int rowb = m0 + wm + mt * 16 + quad * 4;
            #pragma unroll
            for (int r = 0; r < 4; ++r)
                C[(size_t)(rowb + r) * GN + col] = acc[mt][nt][r];
        }
    }
}

// ---------- Kernel 7: scan — one wave per batch, all-register ----------
// All state in NAMED float4 registers (no arrays, no pointer-param lambdas):
// rule #20 — runtime-indexed/pointer-passed private arrays go to scratch.
__global__ __launch_bounds__(64) void scan_kernel(
    const float* __restrict__ sent, const float* __restrict__ hWn,
    const float* __restrict__ u, const float* __restrict__ abs_p,
    const float* __restrict__ rel_vals, const float* __restrict__ bias,
    const int* __restrict__ doc_lens, float* __restrict__ out)
{
    int b = blockIdx.x;
    int lane = threadIdx.x;
    int len = doc_lens[b];
    float lenf = (float)len;

    for (int l = len + lane; l < L_; l += 64) out[b * L_ + l] = 0.f;

    // lane owns cols {lane*4 + j*256 : j=0..3, +0..3}
    const float* ub = u + (size_t)b * D_ + lane * 4;
    float4 ur0 = *(const float4*)(ub);
    float4 ur1 = *(const float4*)(ub + 256);
    float4 ur2 = *(const float4*)(ub + 512);
    float4 ur3 = *(const float4*)(ub + 768);

    float4 s0 = {0.f,0.f,0.f,0.f}, s1 = {0.f,0.f,0.f,0.f};
    float4 s2 = {0.f,0.f,0.f,0.f}, s3 = {0.f,0.f,0.f,0.f};

    const float* sb = sent + (size_t)b * L_ * D_ + lane * 4;
    const float* wb = hWn  + (size_t)b * L_ * D_ + lane * 4;
    float biasv = bias[0];

    float4 hA0, hA1, hA2, hA3, wA0, wA1, wA2, wA3;
    float4 hB0, hB1, hB2, hB3, wB0, wB1, wB2, wB3;

#define LOADROW(row, H0,H1,H2,H3, W0,W1,W2,W3) do { \
    const float* ph_ = sb + (size_t)(row) * D_; \
    const float* pw_ = wb + (size_t)(row) * D_; \
    H0 = *(const float4*)(ph_);       W0 = *(const float4*)(pw_); \
    H1 = *(const float4*)(ph_ + 256); W1 = *(const float4*)(pw_ + 256); \
    H2 = *(const float4*)(ph_ + 512); W2 = *(const float4*)(pw_ + 512); \
    H3 = *(const float4*)(ph_ + 768); W3 = *(const float4*)(pw_ + 768); \
} while (0)

#define DOT4(acc_, X, Y) do { \
    acc_ = fmaf((X).x, (Y).x, acc_); acc_ = fmaf((X).y, (Y).y, acc_); \
    acc_ = fmaf((X).z, (Y).z, acc_); acc_ = fmaf((X).w, (Y).w, acc_); \
} while (0)

#define STEP(t, H0,H1,H2,H3, W0,W1,W2,W3) do { \
    float4 t0_, t1_, t2_, t3_; \
    t0_.x = fast_tanh(s0.x); t0_.y = fast_tanh(s0.y); t0_.z = fast_tanh(s0.z); t0_.w = fast_tanh(s0.w); \
    t1_.x = fast_tanh(s1.x); t1_.y = fast_tanh(s1.y); t1_.z = fast_tanh(s1.z); t1_.w = fast_tanh(s1.w); \
    t2_.x = fast_tanh(s2.x); t2_.y = fast_tanh(s2.y); t2_.z = fast_tanh(s2.z); t2_.w = fast_tanh(s2.w); \
    t3_.x = fast_tanh(s3.x); t3_.y = fast_tanh(s3.y); t3_.z = fast_tanh(s3.z); t3_.w = fast_tanh(s3.w); \
    float r1_ = 0.f, r2_ = 0.f; \
    DOT4(r1_, W0, t0_); DOT4(r1_, W1, t1_); DOT4(r1_, W2, t2_); DOT4(r1_, W3, t3_); \
    DOT4(r2_, H0, ur0); DOT4(r2_, H1, ur1); DOT4(r2_, H2, ur2); DOT4(r2_, H3, ur3); \
    _Pragma("unroll") \
    for (int off_ = 32; off_; off_ >>= 1) { \
        r1_ += __shfl_xor(r1_, off_); \
        r2_ += __shfl_xor(r2_, off_); \
    } \
    int ridx_ = (int)rintf((float)((t) + 1) * 9.0f / lenf); \
    ridx_ = min(max(ridx_, 0), 9); \
    float pre_ = r2_ + abs_p[(t)] + rel_vals[ridx_] + biasv - r1_; \
    float prob_ = fast_sigmoid(pre_); \
    if (lane == 0) out[b * L_ + (t)] = prob_; \
    s0.x = fmaf(prob_, (H0).x, s0.x); s0.y = fmaf(prob_, (H0).y, s0.y); \
    s0.z = fmaf(prob_, (H0).z, s0.z); s0.w = fmaf(prob_, (H0).w, s0.w); \
    s1.x = fmaf(prob_, (H1).x, s1.x); s1.y = fmaf(prob_, (H1).y, s1.y); \
    s1.z = fmaf(prob_, (H1).z, s1.z); s1.w = fmaf(prob_, (H1).w, s1.w); \
    s2.x = fmaf(prob_, (H2).x, s2.x); s2.y = fmaf(prob_, (H2).y, s2.y); \
    s2.z = fmaf(prob_, (H2).z, s2.z); s2.w = fmaf(prob_, (H2).w, s2.w); \
    s3.x = fmaf(prob_, (H3).x, s3.x); s3.y = fmaf(prob_, (H3).y, s3.y); \
    s3.z = fmaf(prob_, (H3).z, s3.z); s3.w = fmaf(prob_, (H3).w, s3.w); \
} while (0)

    LOADROW(0, hA0,hA1,hA2,hA3, wA0,wA1,wA2,wA3);
    int t = 0;
    while (true) {
        int tn = min(t + 1, len - 1);
        LOADROW(tn, hB0,hB1,hB2,hB3, wB0,wB1,wB2,wB3);
        STEP(t, hA0,hA1,hA2,hA3, wA0,wA1,wA2,wA3);
        ++t; if (t >= len) break;
        tn = min(t + 1, len - 1);
        LOADROW(tn, hA0,hA1,hA2,hA3, wA0,wA1,wA2,wA3);
        STEP(t, hB0,hB1,hB2,hB3, wB0,wB1,wB2,wB3);
        ++t; if (t >= len) break;
    }
#undef LOADROW
#undef DOT4
#undef STEP
}

// ---------- launch ----------
extern "C" void kernel_launch(void* const* d_in, const int* in_sizes, int n_in,
                              void* d_out, int out_size, void* d_ws, size_t ws_size,
                              hipStream_t stream)
{
    const float* sent      = (const float*)d_in[0];
    const float* fc_w      = (const float*)d_in[1];
    const float* fc_b      = (const float*)d_in[2];
    const float* content_w = (const float*)d_in[3];
    const float* sal_w     = (const float*)d_in[4];
    const float* nov_w     = (const float*)d_in[5];
    const float* abs_emb   = (const float*)d_in[6];
    const float* rel_emb   = (const float*)d_in[7];
    const float* abs_w     = (const float*)d_in[8];
    const float* rel_w     = (const float*)d_in[9];
    const float* bias      = (const float*)d_in[10];
    const int*   doc_lens  = (const int*)d_in[11];
    float* out = (float*)d_out;

    char* ws = (char*)d_ws;
    const size_t MB = 1024 * 1024;
    _Float16* docs_hi = (_Float16*)(ws);             // 1 MiB
    _Float16* docs_lo = (_Float16*)(ws + 1 * MB);    // 1 MiB
    _Float16* dv_hi   = (_Float16*)(ws + 2 * MB);    // 1 MiB
    _Float16* dv_lo   = (_Float16*)(ws + 3 * MB);    // 1 MiB
    float*    u       = (float*)(ws + 4 * MB);       // 2 MiB
    float*    abs_p   = (float*)(ws + 6 * MB);
    float*    rel_vals= (float*)(ws + 6 * MB + 512);
    _Float16* fcw_hi  = (_Float16*)(ws + 7 * MB);    // 2 MiB
    _Float16* fcw_lo  = (_Float16*)(ws + 9 * MB);    // 2 MiB
    _Float16* salw_hi = (_Float16*)(ws + 11 * MB);   // 2 MiB
    _Float16* salw_lo = (_Float16*)(ws + 13 * MB);   // 2 MiB
    _Float16* Bt_hi   = (_Float16*)(ws + 15 * MB);   // 2 MiB
    _Float16* Bt_lo   = (_Float16*)(ws + 17 * MB);   // 2 MiB
    float*    hWn     = (float*)(ws + 20 * MB);      // 200 MiB

    // 1) docs masked mean + split
    docs_kernel<<<dim3(B_), 256, 0, stream>>>(sent, doc_lens, docs_hi, docs_lo);

    // 2) embedding dots
    emb_kernel<<<dim3(1), 128, 0, stream>>>(abs_emb, rel_emb, abs_w, rel_w, abs_p, rel_vals);

    // 3) split fc_w / sal_w (already [N,K] layout)
    wsplit_kernel<<<dim3(2 * D_ * D_ / (256 * 4)), 256, 0, stream>>>(
        fc_w, sal_w, fcw_hi, fcw_lo, salw_hi, salw_lo);

    // 4) transpose + split nov_w
    convert_b<<<dim3(32, 32), 256, 0, stream>>>(nov_w, Bt_hi, Bt_lo);

    // 5) hWn = sent @ nov_w  (XCD-swizzled 1D grid: 50 groups * 64 blocks)
    gemm_hWn<<<dim3(3200), 256, 0, stream>>>(sent, Bt_hi, Bt_lo, hWn);

    // 6) doc_vec = tanh(docs @ fc_w^T + fc_b) -> f16 pair
    gemm_ms<1><<<dim3(D_ / 128, B_ / 128), 256, 0, stream>>>(
        docs_hi, docs_lo, fcw_hi, fcw_lo, fc_b, nullptr, dv_hi, dv_lo);

    // 7) u = doc_vec @ sal_w^T + content_w -> fp32
    gemm_ms<2><<<dim3(D_ / 128, B_ / 128), 256, 0, stream>>>(
        dv_hi, dv_lo, salw_hi, salw_lo, content_w, u, nullptr, nullptr);

    // 8) scan: one wave per batch
    scan_kernel<<<dim3(B_), 64, 0, stream>>>(
        sent, hWn, u, abs_p, rel_vals, bias, doc_lens, out);
}